// Round 1
// baseline (1329.976 us; speedup 1.0000x reference)
//
#include <hip/hip_runtime.h>
#include <math.h>

// Problem constants (B=8, T=4096, H*D=512, C=64, K=8, CK=512, MODES=32, L=2)
constexpr int NB = 8;
constexpr int NT = 4096;
constexpr int CKN = 512;
constexpr int NMODE = 32;

// ---------------- DFT twiddle tables: tab[t][x][2] = {cos, sin}(2*pi*x*t/n) ----------------
__global__ void build_tables(float* __restrict__ tab, int n) {
  int idx = blockIdx.x * 256 + threadIdx.x;
  if (idx >= n * NMODE) return;
  int t = idx >> 5;
  int x = idx & 31;
  long long tx = ((long long)t * (long long)x) % n;
  double th = 6.28318530717958647692529 * (double)tx / (double)n;
  tab[2 * idx]     = (float)cos(th);
  tab[2 * idx + 1] = (float)sin(th);
}

// ---------------- GEMM: C[M,512] = A[M,512] @ W[512,512] + bias; M=32768 ----------------
// fp32 vector GEMM (no fp32 MFMA on CDNA4). 128x64 tile, 256 thr, 8x4 micro.
__global__ __launch_bounds__(256) void gemm512(
    const float* __restrict__ A, const float* __restrict__ W,
    const float* __restrict__ bias, float* __restrict__ C) {
  __shared__ float As[32][128];  // [k][m]
  __shared__ float Bs[32][64];   // [k][n]
  const int bm = blockIdx.x * 128, bn = blockIdx.y * 64;
  const int tid = threadIdx.x;
  const int tx = tid & 15, ty = tid >> 4;
  float acc[8][4] = {};
  for (int k0 = 0; k0 < 512; k0 += 32) {
#pragma unroll
    for (int r = 0; r < 4; ++r) {
      int i = tid + r * 256;              // 1024 float4 slots
      int m = i >> 3, k4 = (i & 7) << 2;
      float4 v = *(const float4*)&A[(size_t)(bm + m) * 512 + k0 + k4];
      As[k4 + 0][m] = v.x; As[k4 + 1][m] = v.y; As[k4 + 2][m] = v.z; As[k4 + 3][m] = v.w;
    }
#pragma unroll
    for (int r = 0; r < 2; ++r) {
      int i = tid + r * 256;              // 512 float4 slots
      int k = i >> 4, n4 = (i & 15) << 2;
      *(float4*)&Bs[k][n4] = *(const float4*)&W[(size_t)(k0 + k) * 512 + bn + n4];
    }
    __syncthreads();
#pragma unroll
    for (int kk = 0; kk < 32; ++kk) {
      float a[8], bv[4];
      *(float4*)&a[0] = *(const float4*)&As[kk][ty * 8];
      *(float4*)&a[4] = *(const float4*)&As[kk][ty * 8 + 4];
      *(float4*)&bv[0] = *(const float4*)&Bs[kk][tx * 4];
#pragma unroll
      for (int i = 0; i < 8; ++i)
#pragma unroll
        for (int j = 0; j < 4; ++j) acc[i][j] += a[i] * bv[j];
    }
    __syncthreads();
  }
#pragma unroll
  for (int i = 0; i < 8; ++i) {
    float4 o;
    o.x = acc[i][0] + bias[bn + tx * 4 + 0];
    o.y = acc[i][1] + bias[bn + tx * 4 + 1];
    o.z = acc[i][2] + bias[bn + tx * 4 + 2];
    o.w = acc[i][3] + bias[bn + tx * 4 + 3];
    *(float4*)&C[(size_t)(bm + ty * 8 + i) * 512 + bn + tx * 4] = o;
  }
}

// ---------------- wavelet coef: xa=concat(even,odd); dcoef=xa@ec_d; scoef=xa@ec_s ----------------
__global__ __launch_bounds__(256) void coef_kernel(
    const float* __restrict__ cur, const float* __restrict__ ecd,
    const float* __restrict__ ecs, float* __restrict__ dcoef,
    float* __restrict__ scoef, int nhalf) {
  __shared__ float wd[128], ws2[128];
  int tid = threadIdx.x;
  if (tid < 128) { wd[tid] = ecd[tid]; ws2[tid] = ecs[tid]; }
  __syncthreads();
  size_t idx = (size_t)blockIdx.x * 256 + tid;   // over NB*nhalf*64
  int c = (int)(idx & 63);
  int t = (int)((idx >> 6) % (size_t)nhalf);
  int b = (int)(idx / ((size_t)nhalf * 64));
  const float* r0 = cur + ((size_t)b * nhalf * 2 + 2 * (size_t)t) * CKN + c * 8;
  float xa[16];
  *(float4*)&xa[0]  = *(const float4*)&r0[0];
  *(float4*)&xa[4]  = *(const float4*)&r0[4];
  *(float4*)&xa[8]  = *(const float4*)&r0[CKN];
  *(float4*)&xa[12] = *(const float4*)&r0[CKN + 4];
  float d[8] = {}, s[8] = {};
#pragma unroll
  for (int j = 0; j < 16; ++j) {
    float v = xa[j];
#pragma unroll
    for (int k = 0; k < 8; ++k) {
      d[k] += v * wd[j * 8 + k];
      s[k] += v * ws2[j * 8 + k];
    }
  }
  size_t o = ((size_t)b * nhalf + t) * CKN + c * 8;
  *(float4*)&dcoef[o]     = *(float4*)&d[0];
  *(float4*)&dcoef[o + 4] = *(float4*)&d[4];
  *(float4*)&scoef[o]     = *(float4*)&s[0];
  *(float4*)&scoef[o + 4] = *(float4*)&s[4];
}

// ---------------- forward truncated DFT, chunked partials ----------------
// in: (NB, n, 512); part: re/im planes [b][p][x][ck], p-chunk of 64 t's per block.
__global__ __launch_bounds__(256) void fwd_dft_partial(
    const float* __restrict__ in, const float* __restrict__ tab,
    float* __restrict__ part, int n) {
  __shared__ float ltab[64 * 64];   // 64 t-rows x 32 modes x {cos,sin}
  const int p = blockIdx.x, b = blockIdx.y;
  const int P = gridDim.x;
  const int tid = threadIdx.x;
  for (int i = tid; i < 4096; i += 256) ltab[i] = tab[(size_t)p * 4096 + i];
  __syncthreads();
  float ar0[NMODE] = {}, ai0[NMODE] = {}, ar1[NMODE] = {}, ai1[NMODE] = {};
  const float* src = in + ((size_t)b * n + (size_t)p * 64) * CKN + 2 * tid;
#pragma unroll 2
  for (int t = 0; t < 64; ++t) {
    float2 v = *(const float2*)&src[(size_t)t * CKN];
    const float* tr = &ltab[t * 64];
#pragma unroll
    for (int x = 0; x < NMODE; ++x) {
      float c = tr[2 * x], sn = tr[2 * x + 1];
      ar0[x] += v.x * c; ai0[x] -= v.x * sn;
      ar1[x] += v.y * c; ai1[x] -= v.y * sn;
    }
  }
  float* pr = part + ((size_t)b * P + p) * NMODE * CKN + 2 * tid;
  float* pi = pr + (size_t)NB * P * NMODE * CKN;
#pragma unroll
  for (int x = 0; x < NMODE; ++x) {
    float2 r; r.x = ar0[x]; r.y = ar1[x];
    float2 im; im.x = ai0[x]; im.y = ai1[x];
    *(float2*)&pr[(size_t)x * CKN] = r;
    *(float2*)&pi[(size_t)x * CKN] = im;
  }
}

__global__ __launch_bounds__(256) void dft_reduce(
    const float* __restrict__ part, float* __restrict__ fre,
    float* __restrict__ fim, int P) {
  int idx = blockIdx.x * 256 + threadIdx.x;  // NB*32*512 = 131072, idx=(b*32+x)*512+ck
  int ck = idx & 511;
  int x = (idx >> 9) & 31;
  int b = idx >> 14;
  size_t base = ((size_t)b * P * NMODE + x) * CKN + ck;
  size_t ip = (size_t)NB * P * NMODE * CKN;
  size_t ps = (size_t)NMODE * CKN;
  float sr = 0.f, si = 0.f;
  for (int p = 0; p < P; ++p) { sr += part[base + p * ps]; si += part[base + ip + p * ps]; }
  fre[idx] = sr;
  fim[idx] = si;
}

// ---------------- per-mode complex channel-mix, both levels fused ----------------
// freq: 8 planes [lvl(2)][{dRe,dIm,sRe,sIm}][b][x][i], each 131072 floats.
// Out partials over i-chunks: mpart[lvl][chunk8][b][x][o][{UdR,UdI,UsR,UsI}]
__global__ __launch_bounds__(256) void mode_mul(
    const float* __restrict__ freq,
    const float* __restrict__ wAre, const float* __restrict__ wAim,
    const float* __restrict__ wBre, const float* __restrict__ wBim,
    const float* __restrict__ wCre, const float* __restrict__ wCim,
    float* __restrict__ mpart) {
  __shared__ float lf[10240];   // [lvl2][pl4][b8][x32][i4 pad->5] = 40 KB
  const int otile = blockIdx.x, chunk = blockIdx.y;
  const int tid = threadIdx.x;
  const int x = tid & 31, ol = tid >> 5;
  const int o = otile * 8 + ol;
  const int i0 = chunk * 64;
  float acc[2][8][4] = {};
  for (int ii = 0; ii < 64; ii += 4) {
    __syncthreads();
    for (int j = 0; j < 32; ++j) {     // stage 8192 floats
      int idx = tid + j * 256;
      int i = idx & 3, xx = (idx >> 2) & 31, bb = (idx >> 7) & 7;
      int pl = (idx >> 10) & 3, lv = (idx >> 12) & 1;
      lf[(((lv * 4 + pl) * 8 + bb) * 32 + xx) * 5 + i] =
          freq[(size_t)(lv * 4 + pl) * 131072 + ((size_t)bb * 32 + xx) * 512 + i0 + ii + i];
    }
    __syncthreads();
#pragma unroll
    for (int i = 0; i < 4; ++i) {
      int gi = i0 + ii + i;
      size_t wo = ((size_t)gi * 512 + o) * 32 + x;
      float aR = wAre[wo], aI = wAim[wo];
      float bR = wBre[wo], bI = wBim[wo];
      float cR = wCre[wo], cI = wCim[wo];
#pragma unroll
      for (int lv = 0; lv < 2; ++lv)
#pragma unroll
        for (int bq = 0; bq < 8; ++bq) {
          int base = ((lv * 32 + bq) * 32 + x) * 5 + i;   // pl=0 slot
          float dR = lf[base], dI = lf[base + 1280];
          float sR = lf[base + 2560], sI = lf[base + 3840];
          acc[lv][bq][0] += dR * aR - dI * aI + sR * bR - sI * bI;
          acc[lv][bq][1] += dR * aI + dI * aR + sR * bI + sI * bR;
          acc[lv][bq][2] += dR * cR - dI * cI;
          acc[lv][bq][3] += dR * cI + dI * cR;
        }
    }
  }
#pragma unroll
  for (int lv = 0; lv < 2; ++lv)
#pragma unroll
    for (int bq = 0; bq < 8; ++bq) {
      float4 v;
      v.x = acc[lv][bq][0]; v.y = acc[lv][bq][1];
      v.z = acc[lv][bq][2]; v.w = acc[lv][bq][3];
      *(float4*)&mpart[((((size_t)lv * 8 + chunk) * 8 + bq) * 32 + x) * 2048 + o * 4] = v;
    }
}

__global__ __launch_bounds__(256) void mm_reduce(
    const float* __restrict__ mpart, float* __restrict__ outplanes) {
  int idx = blockIdx.x * 256 + threadIdx.x;  // 2*8*32*512 = 262144
  int o = idx & 511;
  int x = (idx >> 9) & 31;
  int b = (idx >> 14) & 7;
  int lvl = idx >> 17;
  float s0 = 0, s1 = 0, s2 = 0, s3 = 0;
  for (int ch = 0; ch < 8; ++ch) {
    const float4 v = *(const float4*)&mpart[((((size_t)lvl * 8 + ch) * 8 + b) * 32 + x) * 2048 + o * 4];
    s0 += v.x; s1 += v.y; s2 += v.z; s3 += v.w;
  }
  size_t fo = ((size_t)b * 32 + x) * 512 + o;
  float* bp = outplanes + (size_t)lvl * 4 * 131072;
  bp[fo] = s0;
  bp[131072 + fo] = s1;
  bp[262144 + fo] = s2;
  bp[393216 + fo] = s3;
}

// ---------------- cur = cur @ t0_w + t0_b (in place, per 8-row) ----------------
__global__ __launch_bounds__(256) void t0_kernel(
    float* __restrict__ cur, const float* __restrict__ w,
    const float* __restrict__ bvec, int rows) {
  __shared__ float lw[64];
  __shared__ float lb[8];
  int tid = threadIdx.x;
  if (tid < 64) lw[tid] = w[tid];
  if (tid < 8) lb[tid] = bvec[tid];
  __syncthreads();
  size_t r = (size_t)blockIdx.x * 256 + tid;
  if (r >= (size_t)rows) return;
  float* p = cur + r * 8;
  float in[8];
  *(float4*)&in[0] = *(const float4*)&p[0];
  *(float4*)&in[4] = *(const float4*)&p[4];
  float outv[8];
#pragma unroll
  for (int k2 = 0; k2 < 8; ++k2) {
    float a = lb[k2];
#pragma unroll
    for (int k = 0; k < 8; ++k) a += in[k] * lw[k * 8 + k2];
    outv[k2] = a;
  }
  *(float4*)&p[0] = *(float4*)&outv[0];
  *(float4*)&p[4] = *(float4*)&outv[4];
}

// ---------------- truncated inverse rDFT (pocketfft c2r semantics, Im X0 ignored) ----------------
__global__ __launch_bounds__(256) void inv_dft(
    const float* __restrict__ fre, const float* __restrict__ fim,
    const float* __restrict__ tab, float* __restrict__ out,
    int n, int beta) {
  __shared__ float ltab[512];    // 8 t-rows x 64
  const int tg = blockIdx.x, b = blockIdx.y;
  const int tid = threadIdx.x;
  for (int i = tid; i < 512; i += 256) ltab[i] = tab[(size_t)tg * 512 + i];
  __syncthreads();
  const int o = tid * 2;
  const float invn = 1.0f / (float)n;
  float fr0[NMODE], fi0[NMODE], fr1[NMODE], fi1[NMODE];
  const float* pr = fre + (size_t)b * NMODE * CKN + o;
  const float* pi = fim + (size_t)b * NMODE * CKN + o;
#pragma unroll
  for (int x = 0; x < NMODE; ++x) {
    float w = (x == 0) ? invn : 2.0f * invn;
    float2 r = *(const float2*)&pr[(size_t)x * CKN];
    float2 im = *(const float2*)&pi[(size_t)x * CKN];
    fr0[x] = r.x * w; fr1[x] = r.y * w;
    fi0[x] = im.x * w; fi1[x] = im.y * w;
  }
  float* dst = out + ((size_t)b * n + (size_t)tg * 8) * CKN + o;
#pragma unroll
  for (int t = 0; t < 8; ++t) {
    const float* tr = &ltab[t * 64];
    float y0 = 0.f, y1 = 0.f;
#pragma unroll
    for (int x = 0; x < NMODE; ++x) {
      float c = tr[2 * x], sn = tr[2 * x + 1];
      y0 += fr0[x] * c - fi0[x] * sn;
      y1 += fr1[x] * c - fi1[x] * sn;
    }
    float2* dp = (float2*)&dst[(size_t)t * CKN];
    float2 yy;
    if (beta) { float2 prev = *dp; yy.x = prev.x + y0; yy.y = prev.y + y1; }
    else { yy.x = y0; yy.y = y1; }
    *dp = yy;
  }
}

// ---------------- reconstruction: cat=[cur,Ud]; even=cat@rc_e, odd=cat@rc_o; interleave ----------------
__global__ __launch_bounds__(256) void recon_kernel(
    const float* __restrict__ cur, const float* __restrict__ ud,
    const float* __restrict__ rce, const float* __restrict__ rco,
    float* __restrict__ out, int n) {
  __shared__ float we[128], wo[128];
  int tid = threadIdx.x;
  if (tid < 128) { we[tid] = rce[tid]; wo[tid] = rco[tid]; }
  __syncthreads();
  size_t idx = (size_t)blockIdx.x * 256 + tid;  // NB*n*64
  int c = (int)(idx & 63);
  int t = (int)((idx >> 6) % (size_t)n);
  int b = (int)(idx / ((size_t)n * 64));
  size_t off = ((size_t)b * n + t) * CKN + c * 8;
  float cat[16];
  *(float4*)&cat[0]  = *(const float4*)&cur[off];
  *(float4*)&cat[4]  = *(const float4*)&cur[off + 4];
  *(float4*)&cat[8]  = *(const float4*)&ud[off];
  *(float4*)&cat[12] = *(const float4*)&ud[off + 4];
  float xe[8] = {}, xo[8] = {};
#pragma unroll
  for (int j = 0; j < 16; ++j) {
    float v = cat[j];
#pragma unroll
    for (int k = 0; k < 8; ++k) {
      xe[k] += v * we[j * 8 + k];
      xo[k] += v * wo[j * 8 + k];
    }
  }
  size_t po = ((size_t)b * 2 * n + 2 * (size_t)t) * CKN + c * 8;
  *(float4*)&out[po]           = *(float4*)&xe[0];
  *(float4*)&out[po + 4]       = *(float4*)&xe[4];
  *(float4*)&out[po + CKN]     = *(float4*)&xo[0];
  *(float4*)&out[po + CKN + 4] = *(float4*)&xo[4];
}

extern "C" void kernel_launch(void* const* d_in, const int* in_sizes, int n_in,
                              void* d_out, int out_size, void* d_ws, size_t ws_size,
                              hipStream_t stream) {
  (void)in_sizes; (void)n_in; (void)out_size; (void)ws_size;
  const float* x         = (const float*)d_in[0];
  const float* lin_in_w  = (const float*)d_in[1];
  const float* lin_in_b  = (const float*)d_in[2];
  const float* lin_out_w = (const float*)d_in[3];
  const float* lin_out_b = (const float*)d_in[4];
  const float* t0_w      = (const float*)d_in[5];
  const float* t0_b      = (const float*)d_in[6];
  const float* wAre      = (const float*)d_in[7];
  const float* wAim      = (const float*)d_in[8];
  const float* wBre      = (const float*)d_in[9];
  const float* wBim      = (const float*)d_in[10];
  const float* wCre      = (const float*)d_in[11];
  const float* wCim      = (const float*)d_in[12];
  const float* ec_s      = (const float*)d_in[13];
  const float* ec_d      = (const float*)d_in[14];
  const float* rc_e      = (const float*)d_in[15];
  const float* rc_o      = (const float*)d_in[16];
  float* ws = (float*)d_ws;
  float* out = (float*)d_out;

  // workspace layout (floats); total 44,236,800 floats = ~177 MB
  float* Z    = ws + 0;          // 16,777,216  (z, later final cur)
  float* D0   = ws + 16777216;   //  8,388,608  (dcoef0, later Ud0)
  float* S0   = ws + 25165824;   //  8,388,608  (scoef0, later level-0 recon cur)
  float* D1   = ws + 33554432;   //  4,194,304  (dcoef1, later Ud1)
  float* S1   = ws + 37748736;   //  4,194,304  (scoef1 / cur1)
  float* F0   = ws + 41943040;   // 16 planes x 131,072
  float* TAB2 = ws + 44040192;   // 131,072
  float* TAB1 = ws + 44171264;   //  65,536
  float* PART = Z;               // overlays Z (free during DFT phase)
  float* MMP  = D0;              // overlays D0+S0 (free during mode-mul phase)

  build_tables<<<(2048 * NMODE + 255) / 256, 256, 0, stream>>>(TAB2, 2048);
  build_tables<<<(1024 * NMODE + 255) / 256, 256, 0, stream>>>(TAB1, 1024);

  // z = x @ lin_in_w + b
  gemm512<<<dim3(256, 8), 256, 0, stream>>>(x, lin_in_w, lin_in_b, Z);

  // level 0: n=4096 -> 2048 coefs
  coef_kernel<<<(NB * 2048 * 64) / 256, 256, 0, stream>>>(Z, ec_d, ec_s, D0, S0, 2048);

  fwd_dft_partial<<<dim3(32, NB), 256, 0, stream>>>(D0, TAB2, PART, 2048);
  dft_reduce<<<512, 256, 0, stream>>>(PART, F0 + 0 * 131072, F0 + 1 * 131072, 32);
  fwd_dft_partial<<<dim3(32, NB), 256, 0, stream>>>(S0, TAB2, PART, 2048);
  dft_reduce<<<512, 256, 0, stream>>>(PART, F0 + 2 * 131072, F0 + 3 * 131072, 32);

  // level 1: n=2048 -> 1024 coefs (from scoef0)
  coef_kernel<<<(NB * 1024 * 64) / 256, 256, 0, stream>>>(S0, ec_d, ec_s, D1, S1, 1024);

  fwd_dft_partial<<<dim3(16, NB), 256, 0, stream>>>(D1, TAB1, PART, 1024);
  dft_reduce<<<512, 256, 0, stream>>>(PART, F0 + 4 * 131072, F0 + 5 * 131072, 16);
  fwd_dft_partial<<<dim3(16, NB), 256, 0, stream>>>(S1, TAB1, PART, 1024);
  dft_reduce<<<512, 256, 0, stream>>>(PART, F0 + 6 * 131072, F0 + 7 * 131072, 16);

  // spectral channel mix, both levels fused (single pass over 201MB of weights)
  mode_mul<<<dim3(64, 8), 256, 0, stream>>>(F0, wAre, wAim, wBre, wBim, wCre, wCim, MMP);
  mm_reduce<<<1024, 256, 0, stream>>>(MMP, F0 + 8 * 131072);

  // cur = scoef1 @ t0_w + t0_b
  t0_kernel<<<(NB * 1024 * 64) / 256, 256, 0, stream>>>(S1, t0_w, t0_b, NB * 1024 * 64);

  // level 1 inverse: cur += irfft(Usf1); Ud1 = irfft(Udf1); reconstruct -> S0 (n=2048)
  inv_dft<<<dim3(128, NB), 256, 0, stream>>>(F0 + 14 * 131072, F0 + 15 * 131072, TAB1, S1, 1024, 1);
  inv_dft<<<dim3(128, NB), 256, 0, stream>>>(F0 + 12 * 131072, F0 + 13 * 131072, TAB1, D1, 1024, 0);
  recon_kernel<<<(NB * 1024 * 64) / 256, 256, 0, stream>>>(S1, D1, rc_e, rc_o, S0, 1024);

  // level 0 inverse: cur += irfft(Usf0); Ud0 = irfft(Udf0); reconstruct -> Z (n=4096)
  inv_dft<<<dim3(256, NB), 256, 0, stream>>>(F0 + 10 * 131072, F0 + 11 * 131072, TAB2, S0, 2048, 1);
  inv_dft<<<dim3(256, NB), 256, 0, stream>>>(F0 + 8 * 131072, F0 + 9 * 131072, TAB2, D0, 2048, 0);
  recon_kernel<<<(NB * 2048 * 64) / 256, 256, 0, stream>>>(S0, D0, rc_e, rc_o, Z, 2048);

  // out = cur @ lin_out_w + b
  gemm512<<<dim3(256, 8), 256, 0, stream>>>(Z, lin_out_w, lin_out_b, out);
}

// Round 2
// 899.087 us; speedup vs baseline: 1.4793x; 1.4793x over previous
//
#include <hip/hip_runtime.h>
#include <math.h>

// Problem constants (B=8, T=4096, H*D=512, C=64, K=8, CK=512, MODES=32, L=2)
constexpr int NB = 8;
constexpr int CKN = 512;
constexpr int NMODE = 32;

typedef __attribute__((ext_vector_type(8))) short short8x;   // 8 bf16 (4 VGPRs)
typedef __attribute__((ext_vector_type(4))) float f32x4;     // 4 fp32 acc

__device__ inline unsigned short f2bf(float f) {
  union { float f; unsigned u; } v; v.f = f;
  unsigned u = v.u;
  unsigned r = (u + 0x7fffu + ((u >> 16) & 1u)) >> 16;   // RNE
  return (unsigned short)r;
}

// ---------------- DFT twiddle tables: tab[t][x][2] = {cos, sin}(2*pi*x*t/n) ----------------
__global__ void build_tables(float* __restrict__ tab, int n) {
  int idx = blockIdx.x * 256 + threadIdx.x;
  if (idx >= n * NMODE) return;
  int t = idx >> 5;
  int x = idx & 31;
  long long tx = ((long long)t * (long long)x) % n;
  double th = 6.28318530717958647692529 * (double)tx / (double)n;
  tab[2 * idx]     = (float)cos(th);
  tab[2 * idx + 1] = (float)sin(th);
}

// ---------------- bf16 MFMA GEMM: C[M,512] = A[M,512] @ W[512,512] + bias ----------------
// fp32 inputs converted to bf16 during LDS staging. BM=128,BN=128,BK=32.
// 256 thr = 4 waves (2x2), each wave 64x64 via 4x4 mfma_f32_16x16x32_bf16 tiles.
__global__ __launch_bounds__(256) void gemm_mfma(
    const float* __restrict__ A, const float* __restrict__ W,
    const float* __restrict__ bias, float* __restrict__ C) {
  __shared__ __align__(16) unsigned short As[128 * 40];  // [m][k] k-contig, stride 40
  __shared__ __align__(16) unsigned short Bs[128 * 40];  // [n][k] k-contig (B^T), stride 40
  const int bm = blockIdx.x * 128, bn = blockIdx.y * 128;
  const int tid = threadIdx.x;
  const int wave = tid >> 6, lane = tid & 63;
  const int wm = (wave >> 1) * 64, wn = (wave & 1) * 64;
  const int lm = lane & 15, quad = lane >> 4;

  f32x4 zero = {0.f, 0.f, 0.f, 0.f};
  f32x4 acc[4][4];
#pragma unroll
  for (int i = 0; i < 4; ++i)
#pragma unroll
    for (int j = 0; j < 4; ++j) acc[i][j] = zero;

  for (int k0 = 0; k0 < 512; k0 += 32) {
    __syncthreads();
    // stage A tile 128x32 (fp32 -> bf16)
#pragma unroll
    for (int r = 0; r < 4; ++r) {
      int slot = tid + r * 256;            // 1024 float4 slots
      int m = slot >> 3, k4 = (slot & 7) << 2;
      float4 v = *(const float4*)&A[(size_t)(bm + m) * 512 + k0 + k4];
      ushort4 u;
      u.x = f2bf(v.x); u.y = f2bf(v.y); u.z = f2bf(v.z); u.w = f2bf(v.w);
      *(ushort4*)&As[m * 40 + k4] = u;
    }
    // stage B tile 32x128 transposed -> Bs[n][k] (fp32 -> bf16)
#pragma unroll
    for (int r = 0; r < 4; ++r) {
      int slot = tid + r * 256;            // 128 n x 8 kgroups
      int n = slot & 127, kg = slot >> 7;
      float w0 = W[(size_t)(k0 + kg * 4 + 0) * 512 + bn + n];
      float w1 = W[(size_t)(k0 + kg * 4 + 1) * 512 + bn + n];
      float w2 = W[(size_t)(k0 + kg * 4 + 2) * 512 + bn + n];
      float w3 = W[(size_t)(k0 + kg * 4 + 3) * 512 + bn + n];
      ushort4 u;
      u.x = f2bf(w0); u.y = f2bf(w1); u.z = f2bf(w2); u.w = f2bf(w3);
      *(ushort4*)&Bs[n * 40 + kg * 4] = u;
    }
    __syncthreads();
    short8x af[4], bf[4];
#pragma unroll
    for (int ti = 0; ti < 4; ++ti)
      af[ti] = *(short8x*)&As[(wm + ti * 16 + lm) * 40 + quad * 8];
#pragma unroll
    for (int tj = 0; tj < 4; ++tj)
      bf[tj] = *(short8x*)&Bs[(wn + tj * 16 + lm) * 40 + quad * 8];
#pragma unroll
    for (int ti = 0; ti < 4; ++ti)
#pragma unroll
      for (int tj = 0; tj < 4; ++tj)
        acc[ti][tj] = __builtin_amdgcn_mfma_f32_16x16x32_bf16(af[ti], bf[tj], acc[ti][tj], 0, 0, 0);
  }
  // epilogue: D row = quad*4 + r, col = lane&15
  float bv[4];
#pragma unroll
  for (int tj = 0; tj < 4; ++tj) bv[tj] = bias[bn + wn + tj * 16 + lm];
#pragma unroll
  for (int ti = 0; ti < 4; ++ti)
#pragma unroll
    for (int tj = 0; tj < 4; ++tj)
#pragma unroll
      for (int r = 0; r < 4; ++r)
        C[(size_t)(bm + wm + ti * 16 + quad * 4 + r) * 512 + bn + wn + tj * 16 + lm] =
            acc[ti][tj][r] + bv[tj];
}

// ---------------- wavelet coef: xa=concat(even,odd); dcoef=xa@ec_d; scoef=xa@ec_s ----------------
__global__ __launch_bounds__(256) void coef_kernel(
    const float* __restrict__ cur, const float* __restrict__ ecd,
    const float* __restrict__ ecs, float* __restrict__ dcoef,
    float* __restrict__ scoef, int nhalf) {
  __shared__ float wd[128], ws2[128];
  int tid = threadIdx.x;
  if (tid < 128) { wd[tid] = ecd[tid]; ws2[tid] = ecs[tid]; }
  __syncthreads();
  size_t idx = (size_t)blockIdx.x * 256 + tid;   // over NB*nhalf*64
  int c = (int)(idx & 63);
  int t = (int)((idx >> 6) % (size_t)nhalf);
  int b = (int)(idx / ((size_t)nhalf * 64));
  const float* r0 = cur + ((size_t)b * nhalf * 2 + 2 * (size_t)t) * CKN + c * 8;
  float xa[16];
  *(float4*)&xa[0]  = *(const float4*)&r0[0];
  *(float4*)&xa[4]  = *(const float4*)&r0[4];
  *(float4*)&xa[8]  = *(const float4*)&r0[CKN];
  *(float4*)&xa[12] = *(const float4*)&r0[CKN + 4];
  float d[8] = {}, s[8] = {};
#pragma unroll
  for (int j = 0; j < 16; ++j) {
    float v = xa[j];
#pragma unroll
    for (int k = 0; k < 8; ++k) {
      d[k] += v * wd[j * 8 + k];
      s[k] += v * ws2[j * 8 + k];
    }
  }
  size_t o = ((size_t)b * nhalf + t) * CKN + c * 8;
  *(float4*)&dcoef[o]     = *(float4*)&d[0];
  *(float4*)&dcoef[o + 4] = *(float4*)&d[4];
  *(float4*)&scoef[o]     = *(float4*)&s[0];
  *(float4*)&scoef[o + 4] = *(float4*)&s[4];
}

// ---------------- forward truncated DFT, chunked partials ----------------
__global__ __launch_bounds__(256) void fwd_dft_partial(
    const float* __restrict__ in, const float* __restrict__ tab,
    float* __restrict__ part, int n) {
  __shared__ float ltab[64 * 64];   // 64 t-rows x 32 modes x {cos,sin}
  const int p = blockIdx.x, b = blockIdx.y;
  const int P = gridDim.x;
  const int tid = threadIdx.x;
  for (int i = tid; i < 4096; i += 256) ltab[i] = tab[(size_t)p * 4096 + i];
  __syncthreads();
  float ar0[NMODE] = {}, ai0[NMODE] = {}, ar1[NMODE] = {}, ai1[NMODE] = {};
  const float* src = in + ((size_t)b * n + (size_t)p * 64) * CKN + 2 * tid;
#pragma unroll 2
  for (int t = 0; t < 64; ++t) {
    float2 v = *(const float2*)&src[(size_t)t * CKN];
    const float* tr = &ltab[t * 64];
#pragma unroll
    for (int x = 0; x < NMODE; ++x) {
      float c = tr[2 * x], sn = tr[2 * x + 1];
      ar0[x] += v.x * c; ai0[x] -= v.x * sn;
      ar1[x] += v.y * c; ai1[x] -= v.y * sn;
    }
  }
  float* pr = part + ((size_t)b * P + p) * NMODE * CKN + 2 * tid;
  float* pi = pr + (size_t)NB * P * NMODE * CKN;
#pragma unroll
  for (int x = 0; x < NMODE; ++x) {
    float2 r; r.x = ar0[x]; r.y = ar1[x];
    float2 im; im.x = ai0[x]; im.y = ai1[x];
    *(float2*)&pr[(size_t)x * CKN] = r;
    *(float2*)&pi[(size_t)x * CKN] = im;
  }
}

__global__ __launch_bounds__(256) void dft_reduce(
    const float* __restrict__ part, float* __restrict__ fre,
    float* __restrict__ fim, int P) {
  int idx = blockIdx.x * 256 + threadIdx.x;  // NB*32*512 = 131072
  int ck = idx & 511;
  int x = (idx >> 9) & 31;
  int b = idx >> 14;
  size_t base = ((size_t)b * P * NMODE + x) * CKN + ck;
  size_t ip = (size_t)NB * P * NMODE * CKN;
  size_t ps = (size_t)NMODE * CKN;
  float sr = 0.f, si = 0.f;
  for (int p = 0; p < P; ++p) { sr += part[base + p * ps]; si += part[base + ip + p * ps]; }
  fre[idx] = sr;
  fim[idx] = si;
}

// ---------------- per-mode complex channel-mix, both levels fused ----------------
// freq: 8 planes [lvl(2)][{dRe,dIm,sRe,sIm}][b][x][i], each 131072 floats.
// partials over i-chunks of 32: mpart[lvl][chunk16][b][x][o][{UdR,UdI,UsR,UsI}]
__global__ __launch_bounds__(256) void mode_mul(
    const float* __restrict__ freq,
    const float* __restrict__ wAre, const float* __restrict__ wAim,
    const float* __restrict__ wBre, const float* __restrict__ wBim,
    const float* __restrict__ wCre, const float* __restrict__ wCim,
    float* __restrict__ mpart) {
  __shared__ __align__(16) float lf[4096];   // [lv2][b8][i4][x32][pl4] = 16 KB
  const int otile = blockIdx.x, chunk = blockIdx.y;
  const int tid = threadIdx.x;
  const int x = tid & 31, ol = tid >> 5;
  const int o = otile * 8 + ol;
  const int i0 = chunk * 32;
  float acc[2][8][4] = {};
  for (int ii = 0; ii < 32; ii += 4) {
    // prefetch weights for the next 4 i's (24 outstanding dwords)
    float wv[4][6];
    size_t wo0 = ((size_t)(i0 + ii) * 512 + o) * 32 + x;
#pragma unroll
    for (int i = 0; i < 4; ++i) {
      size_t wo = wo0 + (size_t)i * 16384;
      wv[i][0] = wAre[wo]; wv[i][1] = wAim[wo];
      wv[i][2] = wBre[wo]; wv[i][3] = wBim[wo];
      wv[i][4] = wCre[wo]; wv[i][5] = wCim[wo];
    }
    __syncthreads();
#pragma unroll
    for (int j = 0; j < 16; ++j) {
      int idx = tid + j * 256;      // 4096 floats
      int il = idx & 3, xx = (idx >> 2) & 31, bb = (idx >> 7) & 7;
      int pl = (idx >> 10) & 3, lv = idx >> 12;
      lf[(((lv * 8 + bb) * 4 + il) * 32 + xx) * 4 + pl] =
          freq[(size_t)(lv * 4 + pl) * 131072 + ((size_t)bb * 32 + xx) * 512 + i0 + ii + il];
    }
    __syncthreads();
#pragma unroll
    for (int i = 0; i < 4; ++i) {
      float aR = wv[i][0], aI = wv[i][1];
      float bR = wv[i][2], bI = wv[i][3];
      float cR = wv[i][4], cI = wv[i][5];
#pragma unroll
      for (int lv = 0; lv < 2; ++lv)
#pragma unroll
        for (int bq = 0; bq < 8; ++bq) {
          float4 f = *(float4*)&lf[(((lv * 8 + bq) * 4 + i) * 32 + x) * 4];  // dR,dI,sR,sI
          acc[lv][bq][0] += f.x * aR - f.y * aI + f.z * bR - f.w * bI;
          acc[lv][bq][1] += f.x * aI + f.y * aR + f.z * bI + f.w * bR;
          acc[lv][bq][2] += f.x * cR - f.y * cI;
          acc[lv][bq][3] += f.x * cI + f.y * cR;
        }
    }
  }
#pragma unroll
  for (int lv = 0; lv < 2; ++lv)
#pragma unroll
    for (int bq = 0; bq < 8; ++bq) {
      float4 v;
      v.x = acc[lv][bq][0]; v.y = acc[lv][bq][1];
      v.z = acc[lv][bq][2]; v.w = acc[lv][bq][3];
      *(float4*)&mpart[((((size_t)lv * 16 + chunk) * 8 + bq) * 32 + x) * 2048 + o * 4] = v;
    }
}

__global__ __launch_bounds__(256) void mm_reduce(
    const float* __restrict__ mpart, float* __restrict__ outplanes) {
  int idx = blockIdx.x * 256 + threadIdx.x;  // 2*8*32*512 = 262144
  int o = idx & 511;
  int x = (idx >> 9) & 31;
  int b = (idx >> 14) & 7;
  int lvl = idx >> 17;
  float s0 = 0, s1 = 0, s2 = 0, s3 = 0;
  for (int ch = 0; ch < 16; ++ch) {
    const float4 v = *(const float4*)&mpart[((((size_t)lvl * 16 + ch) * 8 + b) * 32 + x) * 2048 + o * 4];
    s0 += v.x; s1 += v.y; s2 += v.z; s3 += v.w;
  }
  size_t fo = ((size_t)b * 32 + x) * 512 + o;
  float* bp = outplanes + (size_t)lvl * 4 * 131072;
  bp[fo] = s0;
  bp[131072 + fo] = s1;
  bp[262144 + fo] = s2;
  bp[393216 + fo] = s3;
}

// ---------------- cur = cur @ t0_w + t0_b (in place, per 8-row) ----------------
__global__ __launch_bounds__(256) void t0_kernel(
    float* __restrict__ cur, const float* __restrict__ w,
    const float* __restrict__ bvec, int rows) {
  __shared__ float lw[64];
  __shared__ float lb[8];
  int tid = threadIdx.x;
  if (tid < 64) lw[tid] = w[tid];
  if (tid < 8) lb[tid] = bvec[tid];
  __syncthreads();
  size_t r = (size_t)blockIdx.x * 256 + tid;
  if (r >= (size_t)rows) return;
  float* p = cur + r * 8;
  float in[8];
  *(float4*)&in[0] = *(const float4*)&p[0];
  *(float4*)&in[4] = *(const float4*)&p[4];
  float outv[8];
#pragma unroll
  for (int k2 = 0; k2 < 8; ++k2) {
    float a = lb[k2];
#pragma unroll
    for (int k = 0; k < 8; ++k) a += in[k] * lw[k * 8 + k2];
    outv[k2] = a;
  }
  *(float4*)&p[0] = *(float4*)&outv[0];
  *(float4*)&p[4] = *(float4*)&outv[4];
}

// ---------------- truncated inverse rDFT (pocketfft c2r semantics, Im X0 ignored) ----------------
__global__ __launch_bounds__(256) void inv_dft(
    const float* __restrict__ fre, const float* __restrict__ fim,
    const float* __restrict__ tab, float* __restrict__ out,
    int n, int beta) {
  __shared__ float ltab[512];    // 8 t-rows x 64
  const int tg = blockIdx.x, b = blockIdx.y;
  const int tid = threadIdx.x;
  for (int i = tid; i < 512; i += 256) ltab[i] = tab[(size_t)tg * 512 + i];
  __syncthreads();
  const int o = tid * 2;
  const float invn = 1.0f / (float)n;
  float fr0[NMODE], fi0[NMODE], fr1[NMODE], fi1[NMODE];
  const float* pr = fre + (size_t)b * NMODE * CKN + o;
  const float* pi = fim + (size_t)b * NMODE * CKN + o;
#pragma unroll
  for (int x = 0; x < NMODE; ++x) {
    float w = (x == 0) ? invn : 2.0f * invn;
    float2 r = *(const float2*)&pr[(size_t)x * CKN];
    float2 im = *(const float2*)&pi[(size_t)x * CKN];
    fr0[x] = r.x * w; fr1[x] = r.y * w;
    fi0[x] = im.x * w; fi1[x] = im.y * w;
  }
  float* dst = out + ((size_t)b * n + (size_t)tg * 8) * CKN + o;
#pragma unroll
  for (int t = 0; t < 8; ++t) {
    const float* tr = &ltab[t * 64];
    float y0 = 0.f, y1 = 0.f;
#pragma unroll
    for (int x = 0; x < NMODE; ++x) {
      float c = tr[2 * x], sn = tr[2 * x + 1];
      y0 += fr0[x] * c - fi0[x] * sn;
      y1 += fr1[x] * c - fi1[x] * sn;
    }
    float2* dp = (float2*)&dst[(size_t)t * CKN];
    float2 yy;
    if (beta) { float2 prev = *dp; yy.x = prev.x + y0; yy.y = prev.y + y1; }
    else { yy.x = y0; yy.y = y1; }
    *dp = yy;
  }
}

// ---------------- reconstruction: cat=[cur,Ud]; even=cat@rc_e, odd=cat@rc_o; interleave ----------------
__global__ __launch_bounds__(256) void recon_kernel(
    const float* __restrict__ cur, const float* __restrict__ ud,
    const float* __restrict__ rce, const float* __restrict__ rco,
    float* __restrict__ out, int n) {
  __shared__ float we[128], wo[128];
  int tid = threadIdx.x;
  if (tid < 128) { we[tid] = rce[tid]; wo[tid] = rco[tid]; }
  __syncthreads();
  size_t idx = (size_t)blockIdx.x * 256 + tid;  // NB*n*64
  int c = (int)(idx & 63);
  int t = (int)((idx >> 6) % (size_t)n);
  int b = (int)(idx / ((size_t)n * 64));
  size_t off = ((size_t)b * n + t) * CKN + c * 8;
  float cat[16];
  *(float4*)&cat[0]  = *(const float4*)&cur[off];
  *(float4*)&cat[4]  = *(const float4*)&cur[off + 4];
  *(float4*)&cat[8]  = *(const float4*)&ud[off];
  *(float4*)&cat[12] = *(const float4*)&ud[off + 4];
  float xe[8] = {}, xo[8] = {};
#pragma unroll
  for (int j = 0; j < 16; ++j) {
    float v = cat[j];
#pragma unroll
    for (int k = 0; k < 8; ++k) {
      xe[k] += v * we[j * 8 + k];
      xo[k] += v * wo[j * 8 + k];
    }
  }
  size_t po = ((size_t)b * 2 * n + 2 * (size_t)t) * CKN + c * 8;
  *(float4*)&out[po]           = *(float4*)&xe[0];
  *(float4*)&out[po + 4]       = *(float4*)&xe[4];
  *(float4*)&out[po + CKN]     = *(float4*)&xo[0];
  *(float4*)&out[po + CKN + 4] = *(float4*)&xo[4];
}

extern "C" void kernel_launch(void* const* d_in, const int* in_sizes, int n_in,
                              void* d_out, int out_size, void* d_ws, size_t ws_size,
                              hipStream_t stream) {
  (void)in_sizes; (void)n_in; (void)out_size; (void)ws_size;
  const float* x         = (const float*)d_in[0];
  const float* lin_in_w  = (const float*)d_in[1];
  const float* lin_in_b  = (const float*)d_in[2];
  const float* lin_out_w = (const float*)d_in[3];
  const float* lin_out_b = (const float*)d_in[4];
  const float* t0_w      = (const float*)d_in[5];
  const float* t0_b      = (const float*)d_in[6];
  const float* wAre      = (const float*)d_in[7];
  const float* wAim      = (const float*)d_in[8];
  const float* wBre      = (const float*)d_in[9];
  const float* wBim      = (const float*)d_in[10];
  const float* wCre      = (const float*)d_in[11];
  const float* wCim      = (const float*)d_in[12];
  const float* ec_s      = (const float*)d_in[13];
  const float* ec_d      = (const float*)d_in[14];
  const float* rc_e      = (const float*)d_in[15];
  const float* rc_o      = (const float*)d_in[16];
  float* ws = (float*)d_ws;
  float* out = (float*)d_out;

  // workspace layout (floats)
  float* Z    = ws + 0;          // 16,777,216  (z / final cur; also PART & MMP overlay)
  float* D0   = ws + 16777216;   //  8,388,608  (dcoef0, later Ud0)
  float* S0   = ws + 25165824;   //  8,388,608  (scoef0, later level-0 recon cur)
  float* D1   = ws + 33554432;   //  4,194,304  (dcoef1, later Ud1)
  float* S1   = ws + 37748736;   //  4,194,304  (scoef1 / cur1)
  float* F0   = ws + 41943040;   // 16 planes x 131,072
  float* TAB2 = ws + 44040192;   // 131,072
  float* TAB1 = ws + 44171264;   //  65,536
  float* PART = Z;               // DFT partials overlay (dead z region)
  float* MMP  = Z;               // mode-mul partials overlay (16,777,216 floats exactly)

  build_tables<<<(2048 * NMODE + 255) / 256, 256, 0, stream>>>(TAB2, 2048);
  build_tables<<<(1024 * NMODE + 255) / 256, 256, 0, stream>>>(TAB1, 1024);

  // z = x @ lin_in_w + b   (bf16 MFMA)
  gemm_mfma<<<dim3(256, 4), 256, 0, stream>>>(x, lin_in_w, lin_in_b, Z);

  // level 0: n=4096 -> 2048 coefs
  coef_kernel<<<(NB * 2048 * 64) / 256, 256, 0, stream>>>(Z, ec_d, ec_s, D0, S0, 2048);

  fwd_dft_partial<<<dim3(32, NB), 256, 0, stream>>>(D0, TAB2, PART, 2048);
  dft_reduce<<<512, 256, 0, stream>>>(PART, F0 + 0 * 131072, F0 + 1 * 131072, 32);
  fwd_dft_partial<<<dim3(32, NB), 256, 0, stream>>>(S0, TAB2, PART, 2048);
  dft_reduce<<<512, 256, 0, stream>>>(PART, F0 + 2 * 131072, F0 + 3 * 131072, 32);

  // level 1: n=2048 -> 1024 coefs
  coef_kernel<<<(NB * 1024 * 64) / 256, 256, 0, stream>>>(S0, ec_d, ec_s, D1, S1, 1024);

  fwd_dft_partial<<<dim3(16, NB), 256, 0, stream>>>(D1, TAB1, PART, 1024);
  dft_reduce<<<512, 256, 0, stream>>>(PART, F0 + 4 * 131072, F0 + 5 * 131072, 16);
  fwd_dft_partial<<<dim3(16, NB), 256, 0, stream>>>(S1, TAB1, PART, 1024);
  dft_reduce<<<512, 256, 0, stream>>>(PART, F0 + 6 * 131072, F0 + 7 * 131072, 16);

  // spectral channel mix, both levels fused (single pass over 201MB of weights)
  mode_mul<<<dim3(64, 16), 256, 0, stream>>>(F0, wAre, wAim, wBre, wBim, wCre, wCim, MMP);
  mm_reduce<<<1024, 256, 0, stream>>>(MMP, F0 + 8 * 131072);

  // cur = scoef1 @ t0_w + t0_b
  t0_kernel<<<(NB * 1024 * 64) / 256, 256, 0, stream>>>(S1, t0_w, t0_b, NB * 1024 * 64);

  // level 1 inverse + reconstruction -> S0 (n=2048)
  inv_dft<<<dim3(128, NB), 256, 0, stream>>>(F0 + 14 * 131072, F0 + 15 * 131072, TAB1, S1, 1024, 1);
  inv_dft<<<dim3(128, NB), 256, 0, stream>>>(F0 + 12 * 131072, F0 + 13 * 131072, TAB1, D1, 1024, 0);
  recon_kernel<<<(NB * 1024 * 64) / 256, 256, 0, stream>>>(S1, D1, rc_e, rc_o, S0, 1024);

  // level 0 inverse + reconstruction -> Z (n=4096)
  inv_dft<<<dim3(256, NB), 256, 0, stream>>>(F0 + 10 * 131072, F0 + 11 * 131072, TAB2, S0, 2048, 1);
  inv_dft<<<dim3(256, NB), 256, 0, stream>>>(F0 + 8 * 131072, F0 + 9 * 131072, TAB2, D0, 2048, 0);
  recon_kernel<<<(NB * 2048 * 64) / 256, 256, 0, stream>>>(S0, D0, rc_e, rc_o, Z, 2048);

  // out = cur @ lin_out_w + b   (bf16 MFMA)
  gemm_mfma<<<dim3(256, 4), 256, 0, stream>>>(Z, lin_out_w, lin_out_b, out);
}